// Round 3
// baseline (127.212 us; speedup 1.0000x reference)
//
#include <hip/hip_runtime.h>
#include <hip/hip_bf16.h>

#define BATCH 8192
#define DIM 64
#define TINV 5.0f           // 1 / TEMPERATURE
#define MARGIN 0.8f
#define CGT 1.01831563889f  // 1 + e^-4
#define LGAMMA 0.5f
#define LREG 1e-4f

typedef __attribute__((ext_vector_type(8))) short short8;
typedef __attribute__((ext_vector_type(4))) float float4v;

__device__ __forceinline__ unsigned short f2bf(float f) {
    unsigned int u = __builtin_bit_cast(unsigned int, f);
    unsigned int r = (u + 0x7fffu + ((u >> 16) & 1u)) >> 16;  // round-nearest-even
    return (unsigned short)r;
}

// Phase 1: gather ue/pe/ne (float32 tables), per-row dots & norms; write
// e1 = normalize(ue), g = e1 + normalize(pe) as bf16 for the MFMA phase;
// write per-row pos_score, -logsigmoid(pos-neg), and sum-of-squares.
// One wave per row (lane = dim), grid-stride over rows. No atomics.
__global__ __launch_bounds__(256) void phase1(
    const float* __restrict__ utab,
    const float* __restrict__ itab,
    const int* __restrict__ user, const int* __restrict__ posi,
    const int* __restrict__ negi,
    unsigned short* __restrict__ e1_out, unsigned short* __restrict__ g_out,
    float* __restrict__ pos_score, float* __restrict__ row_bpr,
    float* __restrict__ row_reg)
{
    const int lane = threadIdx.x & 63;
    const int wid = blockIdx.x * 4 + (threadIdx.x >> 6);   // 1024 waves

    for (int r = wid; r < BATCH; r += 1024) {
        const int ui = user[r], pi = posi[r], ni = negi[r];
        const float u = utab[(size_t)ui * DIM + lane];
        const float p = itab[(size_t)pi * DIM + lane];
        const float n = itab[(size_t)ni * DIM + lane];
        float up = u * p, un = u * n, uu = u * u, pp = p * p, nn = n * n;
        #pragma unroll
        for (int off = 32; off; off >>= 1) {
            up += __shfl_xor(up, off);
            un += __shfl_xor(un, off);
            uu += __shfl_xor(uu, off);
            pp += __shfl_xor(pp, off);
            nn += __shfl_xor(nn, off);
        }
        const float nu = fmaxf(sqrtf(uu), 1e-12f);
        const float npn = fmaxf(sqrtf(pp), 1e-12f);
        const float e1 = u / nu;
        const float e2 = p / npn;
        e1_out[r * DIM + lane] = f2bf(e1);
        g_out[r * DIM + lane]  = f2bf(e1 + e2);
        if (lane == 0) {
            const float sim = up / (nu * npn);
            pos_score[r] = __expf(sim * TINV) + __expf(fmaxf(sim - MARGIN, 0.0f) * TINV);
            const float x = up - un;                 // pos - neg (raw embeddings)
            // -logsigmoid(x) = max(-x,0) + log(1 + exp(-|x|))  (stable softplus)
            const float ax = fabsf(x);
            row_bpr[r] = fmaxf(-x, 0.0f) + logf(1.0f + __expf(-ax));
            row_reg[r] = uu + pp + nn;
        }
    }
}

// Phase 2: total[i] = sum_j f(e1_i . g_j) via bf16 MFMA, fused epilogue.
// f(s) = exp(5s) + exp(5*relu(s-0.8)) = (s>m) ? exp(5s)*(1+e^-4) : exp(5s)+1.
// Block: 256 thr = 4 waves. grid = (128 row-stripes, 4 j-slices).
__global__ __launch_bounds__(256) void phase2(
    const unsigned short* __restrict__ e1,
    const unsigned short* __restrict__ g,
    float* __restrict__ total)
{
    const int w = threadIdx.x >> 6;
    const int lane = threadIdx.x & 63;
    const int r0 = blockIdx.x * 64;
    const int jslice = blockIdx.y;          // 0..3, each covers 2048 cols
    const int rowsel = lane & 15;
    const int kbase = (lane >> 4) * 8;      // A/B frag: [m=lane&15][k=quad*8+j]

    short8 a[4][2];
    #pragma unroll
    for (int rt = 0; rt < 4; rt++)
        #pragma unroll
        for (int ks = 0; ks < 2; ks++)
            a[rt][ks] = *(const short8*)&e1[(r0 + rt * 16 + rowsel) * DIM + ks * 32 + kbase];

    float rowacc[4][4];
    #pragma unroll
    for (int rt = 0; rt < 4; rt++)
        #pragma unroll
        for (int q = 0; q < 4; q++) rowacc[rt][q] = 0.0f;

    for (int it = 0; it < 8; it++) {
        const int j0 = jslice * 2048 + it * 256 + w * 64;
        short8 b[4][2];
        #pragma unroll
        for (int ct = 0; ct < 4; ct++)
            #pragma unroll
            for (int ks = 0; ks < 2; ks++)
                b[ct][ks] = *(const short8*)&g[(j0 + ct * 16 + rowsel) * DIM + ks * 32 + kbase];

        #pragma unroll
        for (int rt = 0; rt < 4; rt++) {
            #pragma unroll
            for (int ct = 0; ct < 4; ct++) {
                float4v acc = {0.0f, 0.0f, 0.0f, 0.0f};
                acc = __builtin_amdgcn_mfma_f32_16x16x32_bf16(a[rt][0], b[ct][0], acc, 0, 0, 0);
                acc = __builtin_amdgcn_mfma_f32_16x16x32_bf16(a[rt][1], b[ct][1], acc, 0, 0, 0);
                #pragma unroll
                for (int q = 0; q < 4; q++) {
                    const float s = acc[q];
                    const float e = __expf(s * TINV);
                    const float c = (s > MARGIN) ? CGT : 1.0f;
                    const float d = (s > MARGIN) ? 0.0f : 1.0f;
                    rowacc[rt][q] += fmaf(e, c, d);
                }
            }
        }
    }

    // reduce across the 16 column-lanes (same lane>>4 group holds same rows)
    #pragma unroll
    for (int off = 1; off < 16; off <<= 1)
        #pragma unroll
        for (int rt = 0; rt < 4; rt++)
            #pragma unroll
            for (int q = 0; q < 4; q++)
                rowacc[rt][q] += __shfl_xor(rowacc[rt][q], off);

    if ((lane & 15) == 0) {
        const int rquad = lane >> 4;  // C/D layout: row = quad*4 + q
        #pragma unroll
        for (int rt = 0; rt < 4; rt++)
            #pragma unroll
            for (int q = 0; q < 4; q++)
                atomicAdd(&total[r0 + rt * 16 + rquad * 4 + q], rowacc[rt][q]);
    }
}

// Phase 3: final reductions -> THREE FLOAT32 outputs (bpr, reg, na).
__global__ __launch_bounds__(256) void phase3(
    const float* __restrict__ pos_score, const float* __restrict__ total,
    const float* __restrict__ row_bpr, const float* __restrict__ row_reg,
    float* __restrict__ out)
{
    __shared__ float rb[256], rr[256], rn[256];
    float sb = 0.0f, sr = 0.0f, sn = 0.0f;
    for (int i = threadIdx.x; i < BATCH; i += 256) {
        sb += row_bpr[i];
        sr += row_reg[i];
        sn += -__logf(pos_score[i] / total[i] + 1e-5f);
    }
    rb[threadIdx.x] = sb; rr[threadIdx.x] = sr; rn[threadIdx.x] = sn;
    __syncthreads();
    for (int off = 128; off; off >>= 1) {
        if (threadIdx.x < off) {
            rb[threadIdx.x] += rb[threadIdx.x + off];
            rr[threadIdx.x] += rr[threadIdx.x + off];
            rn[threadIdx.x] += rn[threadIdx.x + off];
        }
        __syncthreads();
    }
    if (threadIdx.x == 0) {
        out[0] = rb[0] / (float)BATCH;                    // bpr
        out[1] = LREG * 0.5f * rr[0] / (float)BATCH;      // reg
        out[2] = LGAMMA * (rn[0] / (float)BATCH);         // na
    }
}

extern "C" void kernel_launch(void* const* d_in, const int* in_sizes, int n_in,
                              void* d_out, int out_size, void* d_ws, size_t ws_size,
                              hipStream_t stream) {
    const float* utab = (const float*)d_in[0];  // float32 [100000,64]
    const float* itab = (const float*)d_in[1];  // float32 [50000,64]
    const int* user = (const int*)d_in[2];
    const int* posi = (const int*)d_in[3];
    const int* negi = (const int*)d_in[4];

    char* ws = (char*)d_ws;
    unsigned short* e1 = (unsigned short*)ws;                              // 1 MB
    unsigned short* g  = (unsigned short*)(ws + (size_t)BATCH * DIM * 2);  // 1 MB
    float* pos_score = (float*)(ws + 2 * (size_t)BATCH * DIM * 2);         // 32 KB
    float* total     = pos_score + BATCH;                                  // 32 KB
    float* row_bpr   = total + BATCH;                                      // 32 KB
    float* row_reg   = row_bpr + BATCH;                                    // 32 KB

    // zero total[] (phase2 accumulates into it with atomics)
    hipMemsetAsync(total, 0, BATCH * sizeof(float), stream);

    phase1<<<256, 256, 0, stream>>>(utab, itab, user, posi, negi,
                                    e1, g, pos_score, row_bpr, row_reg);
    phase2<<<dim3(128, 4), 256, 0, stream>>>(e1, g, total);
    phase3<<<1, 256, 0, stream>>>(pos_score, total, row_bpr, row_reg,
                                  (float*)d_out);
}

// Round 4
// 114.548 us; speedup vs baseline: 1.1106x; 1.1106x over previous
//
#include <hip/hip_runtime.h>
#include <hip/hip_bf16.h>

#define BATCH 8192
#define DIM 64
#define TINV 5.0f              // 1 / TEMPERATURE
#define MARGIN 0.8f
#define SCALE5 7.21347520444f  // 5 * log2(e): A operand pre-scale so MFMA yields log2(exp(sim/T))
#define EM4 0.01831563889f     // e^-4 = 2^(-4*log2 e)
#define LGAMMA 0.5f
#define LREG 1e-4f

typedef __attribute__((ext_vector_type(8))) short short8;
typedef __attribute__((ext_vector_type(4))) float float4v;

__device__ __forceinline__ unsigned short f2bf(float f) {
    unsigned int u = __builtin_bit_cast(unsigned int, f);
    unsigned int r = (u + 0x7fffu + ((u >> 16) & 1u)) >> 16;  // round-nearest-even
    return (unsigned short)r;
}

// Phase 1: 4 rows per wave (float4 per lane, 16-lane groups). Gathers ue/pe/ne,
// computes dots/norms, writes e1*SCALE5 and g = e1 + e2 as bf16, plus per-row
// pos_score / -logsigmoid / sumsq. Also zeroes total[] for phase2's atomics.
// grid: 512 blocks x 256 = 2048 waves = 8192 rows. No loops, no atomics.
__global__ __launch_bounds__(256) void phase1(
    const float* __restrict__ utab,
    const float* __restrict__ itab,
    const int* __restrict__ user, const int* __restrict__ posi,
    const int* __restrict__ negi,
    unsigned short* __restrict__ e1_out, unsigned short* __restrict__ g_out,
    float* __restrict__ pos_score, float* __restrict__ row_bpr,
    float* __restrict__ row_reg, float* __restrict__ total)
{
    const int tid  = blockIdx.x * 256 + threadIdx.x;
    if (tid < BATCH) total[tid] = 0.0f;   // zeroed before phase2 launches (stream order)

    const int lane = threadIdx.x & 63;
    const int wv   = tid >> 6;            // 0..2047
    const int sub  = lane >> 4;           // row within quad
    const int l16  = lane & 15;
    const int r    = wv * 4 + sub;        // this lane's row

    const int ui = user[r], pi = posi[r], ni = negi[r];
    const float4 u = *(const float4*)&utab[(size_t)ui * DIM + l16 * 4];
    const float4 p = *(const float4*)&itab[(size_t)pi * DIM + l16 * 4];
    const float4 n = *(const float4*)&itab[(size_t)ni * DIM + l16 * 4];

    float up = u.x*p.x + u.y*p.y + u.z*p.z + u.w*p.w;
    float un = u.x*n.x + u.y*n.y + u.z*n.z + u.w*n.w;
    float uu = u.x*u.x + u.y*u.y + u.z*u.z + u.w*u.w;
    float pp = p.x*p.x + p.y*p.y + p.z*p.z + p.w*p.w;
    float nn = n.x*n.x + n.y*n.y + n.z*n.z + n.w*n.w;
    #pragma unroll
    for (int off = 1; off < 16; off <<= 1) {   // reduce within 16-lane group
        up += __shfl_xor(up, off);
        un += __shfl_xor(un, off);
        uu += __shfl_xor(uu, off);
        pp += __shfl_xor(pp, off);
        nn += __shfl_xor(nn, off);
    }
    const float nu  = fmaxf(sqrtf(uu), 1e-12f);
    const float npn = fmaxf(sqrtf(pp), 1e-12f);
    const float ia  = 1.0f / nu;     // e1 = u * ia
    const float ib  = 1.0f / npn;    // e2 = p * ib
    const float sa  = SCALE5 * ia;   // scaled-A factor

    union { unsigned short h[4]; uint2 v; } pe1, pg;
    pe1.h[0] = f2bf(u.x * sa); pe1.h[1] = f2bf(u.y * sa);
    pe1.h[2] = f2bf(u.z * sa); pe1.h[3] = f2bf(u.w * sa);
    pg.h[0]  = f2bf(u.x * ia + p.x * ib); pg.h[1] = f2bf(u.y * ia + p.y * ib);
    pg.h[2]  = f2bf(u.z * ia + p.z * ib); pg.h[3] = f2bf(u.w * ia + p.w * ib);
    *(uint2*)&e1_out[r * DIM + l16 * 4] = pe1.v;
    *(uint2*)&g_out[r * DIM + l16 * 4]  = pg.v;

    if (l16 == 0) {
        const float sim = up * (ia * ib);
        pos_score[r] = __expf(sim * TINV) + __expf(fmaxf(sim - MARGIN, 0.0f) * TINV);
        const float x = up - un;   // pos - neg (raw embeddings)
        row_bpr[r] = fmaxf(-x, 0.0f) + __logf(1.0f + __expf(-fabsf(x)));
        row_reg[r] = uu + pp + nn;
    }
}

// Phase 2: total[i] = sum_j f(e1_i . g_j) via bf16 MFMA, fused epilogue.
// A is pre-scaled by 5*log2e, so t = acc gives exp(sim/T) = 2^t and
// f = 2^t + max(2^t * e^-4, 1)   (exact identity for the relu-margin term).
// grid: (128 row-stripes, 8 j-slices) x 256 thr (4 waves) = 4 waves/SIMD.
__global__ __launch_bounds__(256) void phase2(
    const unsigned short* __restrict__ e1,
    const unsigned short* __restrict__ g,
    float* __restrict__ total)
{
    const int w = threadIdx.x >> 6;
    const int lane = threadIdx.x & 63;
    const int r0 = blockIdx.x * 64;
    const int jslice = blockIdx.y;          // 0..7, each covers 1024 cols
    const int rowsel = lane & 15;
    const int kbase = (lane >> 4) * 8;      // A/B frag: [m=lane&15][k=quad*8+j]

    short8 a[4][2];
    #pragma unroll
    for (int rt = 0; rt < 4; rt++)
        #pragma unroll
        for (int ks = 0; ks < 2; ks++)
            a[rt][ks] = *(const short8*)&e1[(r0 + rt * 16 + rowsel) * DIM + ks * 32 + kbase];

    float rowacc[4][4];
    #pragma unroll
    for (int rt = 0; rt < 4; rt++)
        #pragma unroll
        for (int q = 0; q < 4; q++) rowacc[rt][q] = 0.0f;

    for (int it = 0; it < 4; it++) {
        const int j0 = jslice * 1024 + it * 256 + w * 64;
        short8 b[4][2];
        #pragma unroll
        for (int ct = 0; ct < 4; ct++)
            #pragma unroll
            for (int ks = 0; ks < 2; ks++)
                b[ct][ks] = *(const short8*)&g[(j0 + ct * 16 + rowsel) * DIM + ks * 32 + kbase];

        #pragma unroll
        for (int rt = 0; rt < 4; rt++) {
            #pragma unroll
            for (int ct = 0; ct < 4; ct++) {
                float4v acc = {0.0f, 0.0f, 0.0f, 0.0f};
                acc = __builtin_amdgcn_mfma_f32_16x16x32_bf16(a[rt][0], b[ct][0], acc, 0, 0, 0);
                acc = __builtin_amdgcn_mfma_f32_16x16x32_bf16(a[rt][1], b[ct][1], acc, 0, 0, 0);
                #pragma unroll
                for (int q = 0; q < 4; q++) {
                    const float e = exp2f(acc[q]);
                    rowacc[rt][q] += e + fmaxf(e * EM4, 1.0f);
                }
            }
        }
    }

    // reduce across the 16 column-lanes (same lane>>4 group holds same rows)
    #pragma unroll
    for (int off = 1; off < 16; off <<= 1)
        #pragma unroll
        for (int rt = 0; rt < 4; rt++)
            #pragma unroll
            for (int q = 0; q < 4; q++)
                rowacc[rt][q] += __shfl_xor(rowacc[rt][q], off);

    if ((lane & 15) == 0) {
        const int rquad = lane >> 4;  // C/D layout: row = quad*4 + q
        #pragma unroll
        for (int rt = 0; rt < 4; rt++)
            #pragma unroll
            for (int q = 0; q < 4; q++)
                atomicAdd(&total[r0 + rt * 16 + rquad * 4 + q], rowacc[rt][q]);
    }
}

// Phase 3: final reductions -> THREE FLOAT32 outputs (bpr, reg, na).
// 1 block x 1024 threads, shuffle-reduce then LDS across 16 waves.
__global__ __launch_bounds__(1024) void phase3(
    const float* __restrict__ pos_score, const float* __restrict__ total,
    const float* __restrict__ row_bpr, const float* __restrict__ row_reg,
    float* __restrict__ out)
{
    __shared__ float rb[16], rr[16], rn[16];
    float sb = 0.0f, sr = 0.0f, sn = 0.0f;
    for (int i = threadIdx.x; i < BATCH; i += 1024) {
        sb += row_bpr[i];
        sr += row_reg[i];
        sn += -__logf(pos_score[i] / total[i] + 1e-5f);
    }
    #pragma unroll
    for (int off = 32; off; off >>= 1) {
        sb += __shfl_xor(sb, off);
        sr += __shfl_xor(sr, off);
        sn += __shfl_xor(sn, off);
    }
    const int wid = threadIdx.x >> 6;
    if ((threadIdx.x & 63) == 0) { rb[wid] = sb; rr[wid] = sr; rn[wid] = sn; }
    __syncthreads();
    if (threadIdx.x == 0) {
        float tb = 0.0f, tr = 0.0f, tn = 0.0f;
        #pragma unroll
        for (int i = 0; i < 16; i++) { tb += rb[i]; tr += rr[i]; tn += rn[i]; }
        out[0] = tb / (float)BATCH;                    // bpr
        out[1] = LREG * 0.5f * tr / (float)BATCH;      // reg
        out[2] = LGAMMA * (tn / (float)BATCH);         // na
    }
}

extern "C" void kernel_launch(void* const* d_in, const int* in_sizes, int n_in,
                              void* d_out, int out_size, void* d_ws, size_t ws_size,
                              hipStream_t stream) {
    const float* utab = (const float*)d_in[0];  // float32 [100000,64]
    const float* itab = (const float*)d_in[1];  // float32 [50000,64]
    const int* user = (const int*)d_in[2];
    const int* posi = (const int*)d_in[3];
    const int* negi = (const int*)d_in[4];

    char* ws = (char*)d_ws;
    unsigned short* e1 = (unsigned short*)ws;                              // 1 MB
    unsigned short* g  = (unsigned short*)(ws + (size_t)BATCH * DIM * 2);  // 1 MB
    float* pos_score = (float*)(ws + 2 * (size_t)BATCH * DIM * 2);         // 32 KB
    float* total     = pos_score + BATCH;                                  // 32 KB
    float* row_bpr   = total + BATCH;                                      // 32 KB
    float* row_reg   = row_bpr + BATCH;                                    // 32 KB

    phase1<<<512, 256, 0, stream>>>(utab, itab, user, posi, negi,
                                    e1, g, pos_score, row_bpr, row_reg, total);
    phase2<<<dim3(128, 8), 256, 0, stream>>>(e1, g, total);
    phase3<<<1, 1024, 0, stream>>>(pos_score, total, row_bpr, row_reg,
                                   (float*)d_out);
}